// Round 2
// baseline (110.430 us; speedup 1.0000x reference)
//
#include <hip/hip_runtime.h>
#include <hip/hip_fp16.h>

#define KN 64
#define DIN 128
#define DOUT 128
#define NJ 63            // K-1 intervals
#define EPSF 1e-12f
#define HF (1.0f / 63.0f)

// Packed table in d_ws: half4 pk[DIN][NJ][DOUT] = (y0, d0*h, y1, d1*h), 8 B each
// 128*63*128*8 B = 8,257,536 B (~8.26 MB)

__global__ __launch_bounds__(256) void kan_precompute(
    const float* __restrict__ coeffs,   // [DOUT][DIN][KN]
    const float* __restrict__ knots,    // [KN]
    uint2* __restrict__ pk)
{
    const int i      = blockIdx.x >> 1;          // input dim 0..127
    const int o_base = (blockIdx.x & 1) << 6;    // 0 or 64
    const int wave   = threadIdx.x >> 6;         // 0..3
    const int lane   = threadIdx.x & 63;         // knot index k

    __shared__ float ys[64][65];   // [o_local][k], +1 pad -> conflict-free transpose
    __shared__ float ds[64][65];

    // knot spacings (loop-invariant)
    float kn  = knots[lane];
    float kn1 = (lane < 63) ? knots[lane + 1] : 0.0f;
    float hk  = kn1 - kn;                 // h[k], valid lanes 0..62
    float hm1 = __shfl_up(hk, 1);         // h[k-1]
    float h1v = __shfl_down(hk, 1);       // h[k+1]
    float hm2 = __shfl_up(hk, 2);         // h[k-2]

    // Phase 1: wave w computes slopes for o_local = w, w+4, ...
    for (int ol = wave; ol < 64; ol += 4) {
        const int o = o_base + ol;
        float y = coeffs[(o * DIN + i) * KN + lane];
        float ynext = __shfl_down(y, 1);
        float delta = (lane < 63) ? (ynext - y) / (hk + EPSF) : 0.0f;
        float dm1 = __shfl_up(delta, 1);      // delta[k-1]

        // interior slopes (lanes 1..62)
        float w1v = 2.0f * hk + hm1;
        float w2v = hk + 2.0f * hm1;
        float denom = w1v / (dm1 + EPSF) + w2v / (delta + EPSF);
        float d = (dm1 * delta > 0.0f) ? (w1v + w2v) / (denom + EPSF) : 0.0f;

        float d1v = __shfl_down(delta, 1);    // delta[1] for lane 0
        if (lane == 0) {
            float df = ((2.0f * hk + h1v) * delta - hk * d1v) / (hk + h1v + EPSF);
            if (df * delta <= 0.0f) df = 0.0f;
            else if (fabsf(df) > 3.0f * fabsf(delta)) df = 3.0f * delta;
            d = df;
        }
        float dm2 = __shfl_up(delta, 2);      // delta[61] for lane 63
        if (lane == 63) {
            float dl = ((2.0f * hm1 + hm2) * dm1 - hm1 * dm2) / (hm1 + hm2 + EPSF);
            if (dl * dm1 <= 0.0f) dl = 0.0f;
            else if (fabsf(dl) > 3.0f * fabsf(dm1)) dl = 3.0f * dm1;
            d = dl;
        }
        ys[ol][lane] = y;
        ds[ol][lane] = d * HF;                // pre-scale slope by h
    }
    __syncthreads();

    // Phase 2: coalesced writes, lane = o_local (64 lanes x 8 B = 512 B bursts)
    const int ol = threadIdx.x & 63;
    const int jb = threadIdx.x >> 6;          // 0..3
    for (int j = jb; j < NJ; j += 4) {
        __half2 p0 = __floats2half2_rn(ys[ol][j],     ds[ol][j]);
        __half2 p1 = __floats2half2_rn(ys[ol][j + 1], ds[ol][j + 1]);
        uint2 v;
        v.x = *reinterpret_cast<unsigned int*>(&p0);
        v.y = *reinterpret_cast<unsigned int*>(&p1);
        pk[(i * NJ + j) * DOUT + o_base + ol] = v;
    }
}

__global__ __launch_bounds__(128) void kan_main(
    const float* __restrict__ x,        // [B][DIN]
    const uint2* __restrict__ pk,       // [DIN][NJ][DOUT] half4
    const float* __restrict__ bias,     // [DOUT]
    float* __restrict__ out)            // [B][DOUT]
{
    const int b = blockIdx.x;
    const int o = threadIdx.x;          // 0..127

    __shared__ float4 wts[DIN];
    __shared__ int    idxs[DIN];

    const float h = HF;

    // Phase 1: thread t computes Hermite weights for input dim i = t
    float xv = x[b * DIN + o];
    float xc = fminf(fmaxf(xv, 0.0f), 1.0f);
    int idx = (int)floorf(xc / h);
    idx = idx < 0 ? 0 : (idx > 62 ? 62 : idx);
    float t = (xc - (float)idx * h) / h;
    float t2 = t * t, t3 = t2 * t;
    float w0 = 2.0f * t3 - 3.0f * t2 + 1.0f;
    float w1 = t3 - 2.0f * t2 + t;            // slope pre-scaled by h in table
    float w2 = 3.0f * t2 - 2.0f * t3;
    float w3 = t3 - t2;
    if (xv < 0.0f)      { w0 = 1.0f; w1 = xv / h;          w2 = 0.0f; w3 = 0.0f;  idx = 0;  }
    else if (xv > 1.0f) { w0 = 0.0f; w1 = 0.0f; w2 = 1.0f; w3 = (xv - 1.0f) / h;  idx = 62; }
    wts[o]  = make_float4(w0, w1, w2, w3);
    idxs[o] = idx;
    __syncthreads();

    // Phase 2: gather + accumulate (8 B coalesced rows, lane = o)
    float acc0 = 0.0f, acc1 = 0.0f, acc2 = 0.0f, acc3 = 0.0f;
    #pragma unroll 4
    for (int i = 0; i < DIN; i += 4) {
        float4 wA = wts[i];     int jA = idxs[i];
        float4 wB = wts[i + 1]; int jB = idxs[i + 1];
        float4 wC = wts[i + 2]; int jC = idxs[i + 2];
        float4 wD = wts[i + 3]; int jD = idxs[i + 3];
        uint2 qA = pk[((i    ) * NJ + jA) * DOUT + o];
        uint2 qB = pk[((i + 1) * NJ + jB) * DOUT + o];
        uint2 qC = pk[((i + 2) * NJ + jC) * DOUT + o];
        uint2 qD = pk[((i + 3) * NJ + jD) * DOUT + o];
        float2 lA = __half22float2(*reinterpret_cast<const __half2*>(&qA.x));
        float2 hA = __half22float2(*reinterpret_cast<const __half2*>(&qA.y));
        float2 lB = __half22float2(*reinterpret_cast<const __half2*>(&qB.x));
        float2 hB = __half22float2(*reinterpret_cast<const __half2*>(&qB.y));
        float2 lC = __half22float2(*reinterpret_cast<const __half2*>(&qC.x));
        float2 hC = __half22float2(*reinterpret_cast<const __half2*>(&qC.y));
        float2 lD = __half22float2(*reinterpret_cast<const __half2*>(&qD.x));
        float2 hD = __half22float2(*reinterpret_cast<const __half2*>(&qD.y));
        acc0 += wA.x * lA.x + wA.y * lA.y + wA.z * hA.x + wA.w * hA.y;
        acc1 += wB.x * lB.x + wB.y * lB.y + wB.z * hB.x + wB.w * hB.y;
        acc2 += wC.x * lC.x + wC.y * lC.y + wC.z * hC.x + wC.w * hC.y;
        acc3 += wD.x * lD.x + wD.y * lD.y + wD.z * hD.x + wD.w * hD.y;
    }

    out[b * DOUT + o] = acc0 + acc1 + acc2 + acc3 + bias[o];
}

extern "C" void kernel_launch(void* const* d_in, const int* in_sizes, int n_in,
                              void* d_out, int out_size, void* d_ws, size_t ws_size,
                              hipStream_t stream) {
    const float* x      = (const float*)d_in[0];   // 4096*128
    const float* coeffs = (const float*)d_in[1];   // 128*128*64
    const float* bias   = (const float*)d_in[2];   // 128
    const float* knots  = (const float*)d_in[3];   // 64
    float* out = (float*)d_out;
    uint2* pk = (uint2*)d_ws;                      // ~8.26 MB

    // precompute: 128 i x 2 o-halves = 256 blocks, 256 threads
    kan_precompute<<<256, 256, 0, stream>>>(coeffs, knots, pk);
    // main: one block per batch row
    kan_main<<<4096, 128, 0, stream>>>(x, pk, bias, out);
}

// Round 4
// 107.544 us; speedup vs baseline: 1.0268x; 1.0268x over previous
//
#include <hip/hip_runtime.h>

#define KN 64
#define DIN 128
#define DOUT 128
#define EPSF 1e-12f
#define HF (1.0f / 63.0f)

typedef _Float16 h2 __attribute__((ext_vector_type(2)));

#if defined(__has_builtin)
#if __has_builtin(__builtin_amdgcn_fdot2)
#define FDOT2(a, b, c) __builtin_amdgcn_fdot2((a), (b), (c), false)
#endif
#endif
#ifndef FDOT2
static __device__ __forceinline__ float FDOT2(h2 a, h2 b, float c) {
    return c + (float)a.x * (float)b.x + (float)a.y * (float)b.y;
}
#endif

// Table in d_ws: half2 tb[DIN][KN][DOUT] = (y_k, d_k*h)  -> 4 B each
// 128*64*128*4 B = 4,194,304 B = exactly 4 MiB  => per-XCD-L2 resident.

__global__ __launch_bounds__(256) void kan_precompute(
    const float* __restrict__ coeffs,   // [DOUT][DIN][KN]
    const float* __restrict__ knots,    // [KN]
    unsigned int* __restrict__ tb)      // [DIN][KN][DOUT] half2
{
    const int i      = blockIdx.x >> 1;          // input dim 0..127
    const int o_base = (blockIdx.x & 1) << 6;    // 0 or 64
    const int wave   = threadIdx.x >> 6;         // 0..3
    const int lane   = threadIdx.x & 63;         // knot index k

    __shared__ float ys[64][65];   // [o_local][k], +1 pad
    __shared__ float ds[64][65];

    float kn  = knots[lane];
    float kn1 = (lane < 63) ? knots[lane + 1] : 0.0f;
    float hk  = kn1 - kn;                 // h[k], valid lanes 0..62
    float hm1 = __shfl_up(hk, 1);         // h[k-1]
    float h1v = __shfl_down(hk, 1);       // h[k+1]
    float hm2 = __shfl_up(hk, 2);         // h[k-2]

    for (int ol = wave; ol < 64; ol += 4) {
        const int o = o_base + ol;
        float y = coeffs[(o * DIN + i) * KN + lane];
        float ynext = __shfl_down(y, 1);
        float delta = (lane < 63) ? (ynext - y) / (hk + EPSF) : 0.0f;
        float dm1 = __shfl_up(delta, 1);      // delta[k-1]

        // interior slopes (lanes 1..62)
        float w1v = 2.0f * hk + hm1;
        float w2v = hk + 2.0f * hm1;
        float denom = w1v / (dm1 + EPSF) + w2v / (delta + EPSF);
        float d = (dm1 * delta > 0.0f) ? (w1v + w2v) / (denom + EPSF) : 0.0f;

        float d1v = __shfl_down(delta, 1);    // delta[1] for lane 0
        if (lane == 0) {
            float df = ((2.0f * hk + h1v) * delta - hk * d1v) / (hk + h1v + EPSF);
            if (df * delta <= 0.0f) df = 0.0f;
            else if (fabsf(df) > 3.0f * fabsf(delta)) df = 3.0f * delta;
            d = df;
        }
        float dm2 = __shfl_up(delta, 2);      // delta[61] for lane 63
        if (lane == 63) {
            float dl = ((2.0f * hm1 + hm2) * dm1 - hm1 * dm2) / (hm1 + hm2 + EPSF);
            if (dl * dm1 <= 0.0f) dl = 0.0f;
            else if (fabsf(dl) > 3.0f * fabsf(dm1)) dl = 3.0f * dm1;
            d = dl;
        }
        ys[ol][lane] = y;
        ds[ol][lane] = d * HF;                // pre-scale slope by h
    }
    __syncthreads();

    // coalesced writes: lane = o_local, 64 lanes x 4 B = 256 B bursts
    const int ol = threadIdx.x & 63;
    const int kb = threadIdx.x >> 6;          // 0..3
    for (int k = kb; k < KN; k += 4) {
        h2 v;
        v.x = (_Float16)ys[ol][k];
        v.y = (_Float16)ds[ol][k];
        tb[(i * KN + k) * DOUT + o_base + ol] = __builtin_bit_cast(unsigned int, v);
    }
}

__global__ __launch_bounds__(256) void kan_main(
    const float* __restrict__ x,        // [B][DIN]
    const uint2* __restrict__ tb2,      // [DIN][KN][DOUT/2] pairs of half2
    const float* __restrict__ bias,     // [DOUT]
    float* __restrict__ out)            // [B][DOUT]
{
    const int b0   = blockIdx.x << 2;       // 4 batch rows per block
    const int tid  = threadIdx.x;
    const int wv   = tid >> 6;              // wave = local b row
    const int lane = tid & 63;              // lane -> o = 2*lane, 2*lane+1

    __shared__ uint4 wl[4][DIN];            // {w01, w23, idx, pad} per (b_loc, i)

    // Phase 1: weights. 512 (b_loc, i) pairs over 256 threads.
    #pragma unroll
    for (int p = tid; p < 4 * DIN; p += 256) {
        const int bl = p >> 7;
        const int i  = p & 127;
        float xv = x[(b0 + bl) * DIN + i];
        float xc = fminf(fmaxf(xv, 0.0f), 1.0f);
        int idx = (int)floorf(xc * 63.0f);
        idx = idx < 0 ? 0 : (idx > 62 ? 62 : idx);
        float t = xc * 63.0f - (float)idx;
        float t2 = t * t, t3 = t2 * t;
        float w0 = 2.0f * t3 - 3.0f * t2 + 1.0f;
        float w1 = t3 - 2.0f * t2 + t;          // table slope pre-scaled by h
        float w2 = 3.0f * t2 - 2.0f * t3;
        float w3 = t3 - t2;
        if (xv < 0.0f)      { w0 = 1.0f; w1 = xv * 63.0f; w2 = 0.0f; w3 = 0.0f; idx = 0; }
        else if (xv > 1.0f) { w0 = 0.0f; w1 = 0.0f; w2 = 1.0f; w3 = (xv - 1.0f) * 63.0f; idx = 62; }
        h2 w01; w01.x = (_Float16)w0; w01.y = (_Float16)w1;
        h2 w23; w23.x = (_Float16)w2; w23.y = (_Float16)w3;
        uint4 q;
        q.x = __builtin_bit_cast(unsigned int, w01);
        q.y = __builtin_bit_cast(unsigned int, w23);
        q.z = (unsigned int)idx;
        q.w = 0u;
        wl[bl][i] = q;
    }
    __syncthreads();

    // Phase 2: wave wv accumulates batch row b0+wv; lane covers o=2L,2L+1
    float acc0 = 0.0f, acc1 = 0.0f;
    #pragma unroll 8
    for (int i = 0; i < DIN; ++i) {
        uint4 q = wl[wv][i];                              // LDS broadcast
        h2 w01 = __builtin_bit_cast(h2, q.x);
        h2 w23 = __builtin_bit_cast(h2, q.y);
        int base = ((i << 6) + (int)q.z) * 64 + lane;     // uint2 units
        uint2 A = tb2[base];                              // row k=j   (y,dh) x2 o
        uint2 B = tb2[base + 64];                         // row k=j+1
        acc0 = FDOT2(w01, __builtin_bit_cast(h2, A.x), acc0);
        acc0 = FDOT2(w23, __builtin_bit_cast(h2, B.x), acc0);
        acc1 = FDOT2(w01, __builtin_bit_cast(h2, A.y), acc1);
        acc1 = FDOT2(w23, __builtin_bit_cast(h2, B.y), acc1);
    }

    const int o0 = lane << 1;
    float2 bo = *reinterpret_cast<const float2*>(&bias[o0]);
    float2 r; r.x = acc0 + bo.x; r.y = acc1 + bo.y;
    *reinterpret_cast<float2*>(&out[(b0 + wv) * DOUT + o0]) = r;
}

extern "C" void kernel_launch(void* const* d_in, const int* in_sizes, int n_in,
                              void* d_out, int out_size, void* d_ws, size_t ws_size,
                              hipStream_t stream) {
    const float* x      = (const float*)d_in[0];   // 4096*128
    const float* coeffs = (const float*)d_in[1];   // 128*128*64
    const float* bias   = (const float*)d_in[2];   // 128
    const float* knots  = (const float*)d_in[3];   // 64
    float* out = (float*)d_out;
    unsigned int* tb = (unsigned int*)d_ws;        // 4 MiB table

    kan_precompute<<<256, 256, 0, stream>>>(coeffs, knots, tb);
    kan_main<<<1024, 256, 0, stream>>>(x, (const uint2*)tb, bias, out);
}

// Round 5
// 93.778 us; speedup vs baseline: 1.1776x; 1.1468x over previous
//
#include <hip/hip_runtime.h>

#define KN 64
#define DIN 128
#define DOUT 128
#define EPSF 1e-12f
#define HF (1.0f / 63.0f)

typedef _Float16 h2 __attribute__((ext_vector_type(2)));

#if defined(__has_builtin)
#if __has_builtin(__builtin_amdgcn_fdot2)
#define FDOT2(a, b, c) __builtin_amdgcn_fdot2((a), (b), (c), false)
#endif
#endif
#ifndef FDOT2
static __device__ __forceinline__ float FDOT2(h2 a, h2 b, float c) {
    return c + (float)a.x * (float)b.x + (float)a.y * (float)b.y;
}
#endif

// Table in d_ws: interval records, fp16x4 = 8 B each:
//   tb[i][j][o] = (y_j, d_j*h, y_{j+1}, d_{j+1}*h)   j in [0,62], slot 63 unused
// 128 * 64 * 128 * 8 B = 8 MiB. One uint4 load serves o=2L,2L+1.

__global__ __launch_bounds__(256) void kan_precompute(
    const float* __restrict__ coeffs,   // [DOUT][DIN][KN]
    const float* __restrict__ knots,    // [KN]
    uint2* __restrict__ tb)             // [DIN][64][DOUT] 8 B records
{
    const int i      = blockIdx.x >> 2;          // input dim 0..127
    const int o_base = (blockIdx.x & 3) << 5;    // o-quarter: 0,32,64,96
    const int wave   = threadIdx.x >> 6;         // 0..3
    const int lane   = threadIdx.x & 63;         // knot index k

    __shared__ float ys[32][65];   // [o_local][k], +1 pad
    __shared__ float ds[32][65];

    float kn  = knots[lane];
    float kn1 = (lane < 63) ? knots[lane + 1] : 0.0f;
    float hk  = kn1 - kn;                 // h[k], valid lanes 0..62
    float hm1 = __shfl_up(hk, 1);         // h[k-1]
    float h1v = __shfl_down(hk, 1);       // h[k+1]
    float hm2 = __shfl_up(hk, 2);         // h[k-2]

    #pragma unroll
    for (int m = 0; m < 8; ++m) {
        const int ol = wave + (m << 2);          // 0..31 across 4 waves
        const int o  = o_base + ol;
        float y = coeffs[(o * DIN + i) * KN + lane];
        float ynext = __shfl_down(y, 1);
        float delta = (lane < 63) ? (ynext - y) / (hk + EPSF) : 0.0f;
        float dm1 = __shfl_up(delta, 1);      // delta[k-1]

        // interior slopes (lanes 1..62)
        float w1v = 2.0f * hk + hm1;
        float w2v = hk + 2.0f * hm1;
        float denom = w1v / (dm1 + EPSF) + w2v / (delta + EPSF);
        float d = (dm1 * delta > 0.0f) ? (w1v + w2v) / (denom + EPSF) : 0.0f;

        float d1v = __shfl_down(delta, 1);    // delta[1] for lane 0
        if (lane == 0) {
            float df = ((2.0f * hk + h1v) * delta - hk * d1v) / (hk + h1v + EPSF);
            if (df * delta <= 0.0f) df = 0.0f;
            else if (fabsf(df) > 3.0f * fabsf(delta)) df = 3.0f * delta;
            d = df;
        }
        float dm2 = __shfl_up(delta, 2);      // delta[61] for lane 63
        if (lane == 63) {
            float dl = ((2.0f * hm1 + hm2) * dm1 - hm1 * dm2) / (hm1 + hm2 + EPSF);
            if (dl * dm1 <= 0.0f) dl = 0.0f;
            else if (fabsf(dl) > 3.0f * fabsf(dm1)) dl = 3.0f * dm1;
            d = dl;
        }
        ys[ol][lane] = y;
        ds[ol][lane] = d * HF;                // pre-scale slope by h
    }
    __syncthreads();

    // Write interval records: thread -> (ol2 = tid&31, j = tid>>5 + 8*m)
    // Store 8 B at [i][j][o_base+ol2]; lanes 0..31 are 256 B contiguous.
    const int ol2 = threadIdx.x & 31;
    const int j0  = threadIdx.x >> 5;          // 0..7
    #pragma unroll
    for (int m = 0; m < 8; ++m) {
        const int j = j0 + (m << 3);
        if (j < 63) {
            h2 lo; lo.x = (_Float16)ys[ol2][j];     lo.y = (_Float16)ds[ol2][j];
            h2 hi; hi.x = (_Float16)ys[ol2][j + 1]; hi.y = (_Float16)ds[ol2][j + 1];
            uint2 v;
            v.x = __builtin_bit_cast(unsigned int, lo);
            v.y = __builtin_bit_cast(unsigned int, hi);
            tb[((i << 6) + j) * DOUT + o_base + ol2] = v;
        }
    }
}

__global__ __launch_bounds__(256) void kan_main(
    const float* __restrict__ x,        // [B][DIN]
    const uint4* __restrict__ tb4,      // [DIN][64][DOUT/2] 16 B = records for 2 o's
    const float* __restrict__ bias,     // [DOUT]
    float* __restrict__ out)            // [B][DOUT]
{
    const int b0   = blockIdx.x << 1;       // 2 batch rows per block
    const int tid  = threadIdx.x;
    const int wv   = tid >> 6;              // 0..3
    const int bl   = wv >> 1;               // local b row 0..1
    const int half = wv & 1;                // i-range half
    const int lane = tid & 63;              // -> o = 2*lane, 2*lane+1

    __shared__ uint4  wl[2][DIN];           // {w01, w23, idx, pad} per (b_loc, i)
    __shared__ float2 red[2][64];

    // Phase 1: weights. 256 (b_loc, i) pairs over 256 threads, one each.
    {
        const int bl1 = tid >> 7;
        const int i1  = tid & 127;
        float xv = x[(b0 + bl1) * DIN + i1];
        float xc = fminf(fmaxf(xv, 0.0f), 1.0f);
        int idx = (int)floorf(xc * 63.0f);
        idx = idx < 0 ? 0 : (idx > 62 ? 62 : idx);
        float t = xc * 63.0f - (float)idx;
        float t2 = t * t, t3 = t2 * t;
        float w0 = 2.0f * t3 - 3.0f * t2 + 1.0f;
        float w1 = t3 - 2.0f * t2 + t;          // table slope pre-scaled by h
        float w2 = 3.0f * t2 - 2.0f * t3;
        float w3 = t3 - t2;
        if (xv < 0.0f)      { w0 = 1.0f; w1 = xv * 63.0f; w2 = 0.0f; w3 = 0.0f; idx = 0; }
        else if (xv > 1.0f) { w0 = 0.0f; w1 = 0.0f; w2 = 1.0f; w3 = (xv - 1.0f) * 63.0f; idx = 62; }
        h2 w01; w01.x = (_Float16)w0; w01.y = (_Float16)w1;
        h2 w23; w23.x = (_Float16)w2; w23.y = (_Float16)w3;
        uint4 q;
        q.x = __builtin_bit_cast(unsigned int, w01);
        q.y = __builtin_bit_cast(unsigned int, w23);
        q.z = (unsigned int)idx;
        q.w = 0u;
        wl[bl1][i1] = q;
    }
    __syncthreads();

    // Phase 2: wave (bl, half) accumulates i in [half*64, half*64+64)
    float acc0 = 0.0f, acc1 = 0.0f;
    const int ibase = half << 6;
    #pragma unroll 8
    for (int ii = 0; ii < 64; ++ii) {
        const int i = ibase + ii;
        uint4 q = wl[bl][i];                              // LDS broadcast (b128)
        h2 w01 = __builtin_bit_cast(h2, q.x);
        h2 w23 = __builtin_bit_cast(h2, q.y);
        // uint4 index: (i*64 + j)*64 + lane  (32-bit voffset from SGPR base)
        unsigned off = (((unsigned)(i << 6) + q.z) << 6) + (unsigned)lane;
        uint4 r = tb4[off];
        acc0 = FDOT2(w01, __builtin_bit_cast(h2, r.x), acc0);
        acc0 = FDOT2(w23, __builtin_bit_cast(h2, r.y), acc0);
        acc1 = FDOT2(w01, __builtin_bit_cast(h2, r.z), acc1);
        acc1 = FDOT2(w23, __builtin_bit_cast(h2, r.w), acc1);
    }

    // Cross-wave reduce (half 1 -> half 0), then store
    if (half) red[bl][lane] = make_float2(acc0, acc1);
    __syncthreads();
    if (!half) {
        float2 r2 = red[bl][lane];
        const int o0 = lane << 1;
        float2 bo = *reinterpret_cast<const float2*>(&bias[o0]);
        float2 res;
        res.x = acc0 + r2.x + bo.x;
        res.y = acc1 + r2.y + bo.y;
        *reinterpret_cast<float2*>(&out[(b0 + bl) * DOUT + o0]) = res;
    }
}

extern "C" void kernel_launch(void* const* d_in, const int* in_sizes, int n_in,
                              void* d_out, int out_size, void* d_ws, size_t ws_size,
                              hipStream_t stream) {
    const float* x      = (const float*)d_in[0];   // 4096*128
    const float* coeffs = (const float*)d_in[1];   // 128*128*64
    const float* bias   = (const float*)d_in[2];   // 128
    const float* knots  = (const float*)d_in[3];   // 64
    float* out = (float*)d_out;
    uint2* tb = (uint2*)d_ws;                      // 8 MiB interval table

    // 128 i x 4 o-quarters = 512... -> 1024 blocks for 4 blocks/CU
    kan_precompute<<<512, 256, 0, stream>>>(coeffs, knots, tb);
    kan_main<<<2048, 256, 0, stream>>>(x, (const uint4*)tb, bias, out);
}